// Round 1
// baseline (185.951 us; speedup 1.0000x reference)
//
#include <hip/hip_runtime.h>

#define EPS 1e-5
constexpr int BLOCK = 256;

// ---------------- stats: per-channel sums + cross products (fp64) ----------
// grid = (Bx, 2): y selects image. acc[9*y + {s0,s1,s2,q00,q01,q02,q11,q12,q22}]
__global__ void stats_kernel(const float* __restrict__ in0,
                             const float* __restrict__ in1,
                             double* __restrict__ acc, int n4) {
    const float4* base = (const float4*)(blockIdx.y == 0 ? in0 : in1);
    double* out = acc + 9 * blockIdx.y;
    double s0 = 0, s1 = 0, s2 = 0;
    double q00 = 0, q01 = 0, q02 = 0, q11 = 0, q12 = 0, q22 = 0;
    int stride = gridDim.x * blockDim.x;
    for (int i = blockIdx.x * blockDim.x + threadIdx.x; i < n4; i += stride) {
        float4 a = base[i];
        float4 b = base[i + n4];
        float4 c = base[i + 2 * n4];
#define ACC(f) { double x = (double)a.f, y = (double)b.f, z = (double)c.f;      \
        s0 += x; s1 += y; s2 += z;                                              \
        q00 = fma(x, x, q00); q01 = fma(x, y, q01); q02 = fma(x, z, q02);       \
        q11 = fma(y, y, q11); q12 = fma(y, z, q12); q22 = fma(z, z, q22); }
        ACC(x) ACC(y) ACC(z) ACC(w)
#undef ACC
    }
    double v[9] = {s0, s1, s2, q00, q01, q02, q11, q12, q22};
    int lane = threadIdx.x & 63;
    int wid  = threadIdx.x >> 6;
    __shared__ double sh[BLOCK / 64][9];
#pragma unroll
    for (int j = 0; j < 9; ++j) {
        double t = v[j];
#pragma unroll
        for (int o = 32; o > 0; o >>= 1) t += __shfl_down(t, o, 64);
        if (lane == 0) sh[wid][j] = t;
    }
    __syncthreads();
    if (threadIdx.x == 0) {
#pragma unroll
        for (int j = 0; j < 9; ++j) {
            double t = 0;
#pragma unroll
            for (int wv = 0; wv < BLOCK / 64; ++wv) t += sh[wv][j];
            atomicAdd(&out[j], t);
        }
    }
}

// ---------------- 3x3 symmetric Jacobi eigendecomposition ------------------
__device__ void jacobi3(const double Ain[3][3], double w[3], double V[3][3]) {
    double A[3][3];
    for (int i = 0; i < 3; ++i)
        for (int j = 0; j < 3; ++j) {
            A[i][j] = Ain[i][j];
            V[i][j] = (i == j) ? 1.0 : 0.0;
        }
    const int pp[3] = {0, 0, 1};
    const int qq[3] = {1, 2, 2};
    for (int sweep = 0; sweep < 50; ++sweep) {
        double off = A[0][1]*A[0][1] + A[0][2]*A[0][2] + A[1][2]*A[1][2];
        if (off < 1e-28) break;
        for (int r3 = 0; r3 < 3; ++r3) {
            int p = pp[r3], q = qq[r3];
            double apq = A[p][q];
            if (apq == 0.0) continue;
            double theta = (A[q][q] - A[p][p]) / (2.0 * apq);
            double t = ((theta >= 0.0) ? 1.0 : -1.0) /
                       (fabs(theta) + sqrt(theta * theta + 1.0));
            double c = 1.0 / sqrt(t * t + 1.0);
            double s = t * c;
            A[p][p] -= t * apq;
            A[q][q] += t * apq;
            A[p][q] = A[q][p] = 0.0;
            int r = 3 - p - q;
            double arp = A[r][p], arq = A[r][q];
            A[r][p] = A[p][r] = c * arp - s * arq;
            A[r][q] = A[q][r] = s * arp + c * arq;
            for (int k = 0; k < 3; ++k) {
                double vkp = V[k][p], vkq = V[k][q];
                V[k][p] = c * vkp - s * vkq;
                V[k][q] = s * vkp + c * vkq;
            }
        }
    }
    w[0] = A[0][0]; w[1] = A[1][1]; w[2] = A[2][2];
}

// P = V * diag(f(w)) * V^T,  f = sqrt (or 1/sqrt if invert), nan/neg -> 0
__device__ void pca_pow(const double w[3], const double V[3][3], bool invert,
                        double P[3][3]) {
    double e[3];
    for (int k = 0; k < 3; ++k) {
        double ek = (w[k] > 0.0) ? sqrt(w[k]) : 0.0;
        if (invert) ek = (ek > 0.0) ? 1.0 / ek : 0.0;
        e[k] = ek;
    }
    for (int i = 0; i < 3; ++i)
        for (int j = 0; j < 3; ++j) {
            double t = 0;
            for (int k = 0; k < 3; ++k) t += V[i][k] * e[k] * V[j][k];
            P[i][j] = t;
        }
}

// ---------------- solve: build T (3x3) + bias (3) --------------------------
__global__ void solve_kernel(const double* __restrict__ acc,
                             float* __restrict__ tb, double inv_n) {
    double mean[2][3];
    double P[2][3][3];   // P[0] = invsqrtm(ct), P[1] = sqrtm(cs)
    for (int im = 0; im < 2; ++im) {
        const double* a = acc + 9 * im;
        double m0 = a[0] * inv_n, m1 = a[1] * inv_n, m2 = a[2] * inv_n;
        mean[im][0] = m0; mean[im][1] = m1; mean[im][2] = m2;
        double C[3][3];
        C[0][0] = a[3] * inv_n - m0 * m0 + EPS;
        C[0][1] = C[1][0] = a[4] * inv_n - m0 * m1;
        C[0][2] = C[2][0] = a[5] * inv_n - m0 * m2;
        C[1][1] = a[6] * inv_n - m1 * m1 + EPS;
        C[1][2] = C[2][1] = a[7] * inv_n - m1 * m2;
        C[2][2] = a[8] * inv_n - m2 * m2 + EPS;
        double w[3], V[3][3];
        jacobi3(C, w, V);
        pca_pow(w, V, im == 0 /* invert for target */, P[im]);
    }
    // T = sqrtm(cs) @ invsqrtm(ct)  = P[1] @ P[0]
    double T[3][3];
    for (int i = 0; i < 3; ++i)
        for (int j = 0; j < 3; ++j) {
            double t = 0;
            for (int k = 0; k < 3; ++k) t += P[1][i][k] * P[0][k][j];
            T[i][j] = t;
        }
    for (int i = 0; i < 3; ++i) {
        double b = mean[1][i];
        for (int k = 0; k < 3; ++k) b -= T[i][k] * mean[0][k];
        tb[3 * i + 0] = (float)T[i][0];
        tb[3 * i + 1] = (float)T[i][1];
        tb[3 * i + 2] = (float)T[i][2];
        tb[9 + i] = (float)b;
    }
}

// ---------------- apply: out = T*(in) + bias (mean folded into bias) -------
__global__ void apply_kernel(const float* __restrict__ in,
                             const float* __restrict__ tb,
                             float* __restrict__ out, int n4) {
    float t00 = tb[0], t01 = tb[1], t02 = tb[2];
    float t10 = tb[3], t11 = tb[4], t12 = tb[5];
    float t20 = tb[6], t21 = tb[7], t22 = tb[8];
    float b0 = tb[9], b1 = tb[10], b2 = tb[11];
    const float4* a = (const float4*)in;
    float4* o = (float4*)out;
    int stride = gridDim.x * blockDim.x;
    for (int i = blockIdx.x * blockDim.x + threadIdx.x; i < n4; i += stride) {
        float4 x = a[i];
        float4 y = a[i + n4];
        float4 z = a[i + 2 * n4];
        float4 r0, r1, r2;
#define AP(f) r0.f = fmaf(t00, x.f, fmaf(t01, y.f, fmaf(t02, z.f, b0)));       \
              r1.f = fmaf(t10, x.f, fmaf(t11, y.f, fmaf(t12, z.f, b1)));       \
              r2.f = fmaf(t20, x.f, fmaf(t21, y.f, fmaf(t22, z.f, b2)));
        AP(x) AP(y) AP(z) AP(w)
#undef AP
        o[i] = r0;
        o[i + n4] = r1;
        o[i + 2 * n4] = r2;
    }
}

extern "C" void kernel_launch(void* const* d_in, const int* in_sizes, int n_in,
                              void* d_out, int out_size, void* d_ws, size_t ws_size,
                              hipStream_t stream) {
    const float* in0 = (const float*)d_in[0];  // input (target)
    const float* in1 = (const float*)d_in[1];  // source_tensor
    float* out = (float*)d_out;
    int total = in_sizes[0];     // 3 * H * W
    int n = total / 3;           // plane size H*W
    int n4 = n / 4;              // float4 count per plane

    double* acc = (double*)d_ws;                       // 18 doubles
    float* tb = (float*)((char*)d_ws + 256);           // T(9) + bias(3)

    hipMemsetAsync(d_ws, 0, 18 * sizeof(double), stream);

    dim3 sgrid(1024, 2);
    stats_kernel<<<sgrid, BLOCK, 0, stream>>>(in0, in1, acc, n4);
    solve_kernel<<<1, 1, 0, stream>>>(acc, tb, 1.0 / (double)n);
    apply_kernel<<<2048, BLOCK, 0, stream>>>(in0, tb, out, n4);
}

// Round 2
// 55.356 us; speedup vs baseline: 3.3592x; 3.3592x over previous
//
#include <hip/hip_runtime.h>

#define EPS 1e-5
constexpr int BLOCK = 256;
constexpr int SBLOCKS = 512;   // stats blocks per image

// ---------------- stats: per-channel sums + cross products (fp64) ----------
// grid = (SBLOCKS, 2): y selects image.
// partials[(img*SBLOCKS + blk)*9 + {s0,s1,s2,q00,q01,q02,q11,q12,q22}]
__global__ void stats_kernel(const float* __restrict__ in0,
                             const float* __restrict__ in1,
                             double* __restrict__ partials, int n4) {
    const float4* base = (const float4*)(blockIdx.y == 0 ? in0 : in1);
    double s0 = 0, s1 = 0, s2 = 0;
    double q00 = 0, q01 = 0, q02 = 0, q11 = 0, q12 = 0, q22 = 0;
    int stride = gridDim.x * blockDim.x;
    for (int i = blockIdx.x * blockDim.x + threadIdx.x; i < n4; i += stride) {
        float4 a = base[i];
        float4 b = base[i + n4];
        float4 c = base[i + 2 * n4];
#define ACC(f) { double x = (double)a.f, y = (double)b.f, z = (double)c.f;      \
        s0 += x; s1 += y; s2 += z;                                              \
        q00 = fma(x, x, q00); q01 = fma(x, y, q01); q02 = fma(x, z, q02);       \
        q11 = fma(y, y, q11); q12 = fma(y, z, q12); q22 = fma(z, z, q22); }
        ACC(x) ACC(y) ACC(z) ACC(w)
#undef ACC
    }
    double v[9] = {s0, s1, s2, q00, q01, q02, q11, q12, q22};
    int lane = threadIdx.x & 63;
    int wid  = threadIdx.x >> 6;
    __shared__ double sh[BLOCK / 64][9];
#pragma unroll
    for (int j = 0; j < 9; ++j) {
        double t = v[j];
#pragma unroll
        for (int o = 32; o > 0; o >>= 1) t += __shfl_down(t, o, 64);
        if (lane == 0) sh[wid][j] = t;
    }
    __syncthreads();
    if (threadIdx.x == 0) {
        double* out = partials + (blockIdx.y * SBLOCKS + blockIdx.x) * 9;
#pragma unroll
        for (int j = 0; j < 9; ++j) {
            double t = 0;
#pragma unroll
            for (int wv = 0; wv < BLOCK / 64; ++wv) t += sh[wv][j];
            out[j] = t;
        }
    }
}

// ---------------- 3x3 symmetric Jacobi eigendecomposition ------------------
__device__ void jacobi3(const double Ain[3][3], double w[3], double V[3][3]) {
    double A[3][3];
    for (int i = 0; i < 3; ++i)
        for (int j = 0; j < 3; ++j) {
            A[i][j] = Ain[i][j];
            V[i][j] = (i == j) ? 1.0 : 0.0;
        }
    const int pp[3] = {0, 0, 1};
    const int qq[3] = {1, 2, 2};
    for (int sweep = 0; sweep < 50; ++sweep) {
        double off = A[0][1]*A[0][1] + A[0][2]*A[0][2] + A[1][2]*A[1][2];
        if (off < 1e-28) break;
        for (int r3 = 0; r3 < 3; ++r3) {
            int p = pp[r3], q = qq[r3];
            double apq = A[p][q];
            if (apq == 0.0) continue;
            double theta = (A[q][q] - A[p][p]) / (2.0 * apq);
            double t = ((theta >= 0.0) ? 1.0 : -1.0) /
                       (fabs(theta) + sqrt(theta * theta + 1.0));
            double c = 1.0 / sqrt(t * t + 1.0);
            double s = t * c;
            A[p][p] -= t * apq;
            A[q][q] += t * apq;
            A[p][q] = A[q][p] = 0.0;
            int r = 3 - p - q;
            double arp = A[r][p], arq = A[r][q];
            A[r][p] = A[p][r] = c * arp - s * arq;
            A[r][q] = A[q][r] = s * arp + c * arq;
            for (int k = 0; k < 3; ++k) {
                double vkp = V[k][p], vkq = V[k][q];
                V[k][p] = c * vkp - s * vkq;
                V[k][q] = s * vkp + c * vkq;
            }
        }
    }
    w[0] = A[0][0]; w[1] = A[1][1]; w[2] = A[2][2];
}

// P = V * diag(f(w)) * V^T,  f = sqrt (or 1/sqrt if invert), nan/neg -> 0
__device__ void pca_pow(const double w[3], const double V[3][3], bool invert,
                        double P[3][3]) {
    double e[3];
    for (int k = 0; k < 3; ++k) {
        double ek = (w[k] > 0.0) ? sqrt(w[k]) : 0.0;
        if (invert) ek = (ek > 0.0) ? 1.0 / ek : 0.0;
        e[k] = ek;
    }
    for (int i = 0; i < 3; ++i)
        for (int j = 0; j < 3; ++j) {
            double t = 0;
            for (int k = 0; k < 3; ++k) t += V[i][k] * e[k] * V[j][k];
            P[i][j] = t;
        }
}

// ---------------- solve: reduce partials, build T (3x3) + bias (3) --------
// one block of 256 threads; each thread owns 2 partial slots per image.
__global__ void solve_kernel(const double* __restrict__ partials,
                             float* __restrict__ tb, double inv_n) {
    __shared__ double ssum[2][9];
    __shared__ double sh[BLOCK / 64][9];
    int lane = threadIdx.x & 63;
    int wid  = threadIdx.x >> 6;
    for (int img = 0; img < 2; ++img) {
        const double* p0 = partials + (img * SBLOCKS + threadIdx.x) * 9;
        const double* p1 = p0 + BLOCK * 9;
        double v[9];
#pragma unroll
        for (int j = 0; j < 9; ++j) v[j] = p0[j] + p1[j];
#pragma unroll
        for (int j = 0; j < 9; ++j) {
            double t = v[j];
#pragma unroll
            for (int o = 32; o > 0; o >>= 1) t += __shfl_down(t, o, 64);
            if (lane == 0) sh[wid][j] = t;
        }
        __syncthreads();
        if (threadIdx.x == 0) {
#pragma unroll
            for (int j = 0; j < 9; ++j)
                ssum[img][j] = sh[0][j] + sh[1][j] + sh[2][j] + sh[3][j];
        }
        __syncthreads();
    }
    if (threadIdx.x != 0) return;

    double mean[2][3];
    double P[2][3][3];   // P[0] = invsqrtm(ct), P[1] = sqrtm(cs)
    for (int im = 0; im < 2; ++im) {
        const double* a = ssum[im];
        double m0 = a[0] * inv_n, m1 = a[1] * inv_n, m2 = a[2] * inv_n;
        mean[im][0] = m0; mean[im][1] = m1; mean[im][2] = m2;
        double C[3][3];
        C[0][0] = a[3] * inv_n - m0 * m0 + EPS;
        C[0][1] = C[1][0] = a[4] * inv_n - m0 * m1;
        C[0][2] = C[2][0] = a[5] * inv_n - m0 * m2;
        C[1][1] = a[6] * inv_n - m1 * m1 + EPS;
        C[1][2] = C[2][1] = a[7] * inv_n - m1 * m2;
        C[2][2] = a[8] * inv_n - m2 * m2 + EPS;
        double w[3], V[3][3];
        jacobi3(C, w, V);
        pca_pow(w, V, im == 0 /* invert for target */, P[im]);
    }
    // T = sqrtm(cs) @ invsqrtm(ct) = P[1] @ P[0]
    double T[3][3];
    for (int i = 0; i < 3; ++i)
        for (int j = 0; j < 3; ++j) {
            double t = 0;
            for (int k = 0; k < 3; ++k) t += P[1][i][k] * P[0][k][j];
            T[i][j] = t;
        }
    for (int i = 0; i < 3; ++i) {
        double b = mean[1][i];
        for (int k = 0; k < 3; ++k) b -= T[i][k] * mean[0][k];
        tb[3 * i + 0] = (float)T[i][0];
        tb[3 * i + 1] = (float)T[i][1];
        tb[3 * i + 2] = (float)T[i][2];
        tb[9 + i] = (float)b;
    }
}

// ---------------- apply: out = T*in + bias (means folded into bias) --------
__global__ void apply_kernel(const float* __restrict__ in,
                             const float* __restrict__ tb,
                             float* __restrict__ out, int n4) {
    float t00 = tb[0], t01 = tb[1], t02 = tb[2];
    float t10 = tb[3], t11 = tb[4], t12 = tb[5];
    float t20 = tb[6], t21 = tb[7], t22 = tb[8];
    float b0 = tb[9], b1 = tb[10], b2 = tb[11];
    const float4* a = (const float4*)in;
    float4* o = (float4*)out;
    int stride = gridDim.x * blockDim.x;
    for (int i = blockIdx.x * blockDim.x + threadIdx.x; i < n4; i += stride) {
        float4 x = a[i];
        float4 y = a[i + n4];
        float4 z = a[i + 2 * n4];
        float4 r0, r1, r2;
#define AP(f) r0.f = fmaf(t00, x.f, fmaf(t01, y.f, fmaf(t02, z.f, b0)));       \
              r1.f = fmaf(t10, x.f, fmaf(t11, y.f, fmaf(t12, z.f, b1)));       \
              r2.f = fmaf(t20, x.f, fmaf(t21, y.f, fmaf(t22, z.f, b2)));
        AP(x) AP(y) AP(z) AP(w)
#undef AP
        o[i] = r0;
        o[i + n4] = r1;
        o[i + 2 * n4] = r2;
    }
}

extern "C" void kernel_launch(void* const* d_in, const int* in_sizes, int n_in,
                              void* d_out, int out_size, void* d_ws, size_t ws_size,
                              hipStream_t stream) {
    const float* in0 = (const float*)d_in[0];  // input (target)
    const float* in1 = (const float*)d_in[1];  // source_tensor
    float* out = (float*)d_out;
    int total = in_sizes[0];     // 3 * H * W
    int n = total / 3;           // plane size H*W
    int n4 = n / 4;              // float4 count per plane

    double* partials = (double*)d_ws;                        // 2*512*9 doubles = 72 KB
    float* tb = (float*)((char*)d_ws + 2 * SBLOCKS * 9 * sizeof(double));

    dim3 sgrid(SBLOCKS, 2);
    stats_kernel<<<sgrid, BLOCK, 0, stream>>>(in0, in1, partials, n4);
    solve_kernel<<<1, BLOCK, 0, stream>>>(partials, tb, 1.0 / (double)n);
    apply_kernel<<<2048, BLOCK, 0, stream>>>(in0, tb, out, n4);
}